// Round 1
// baseline (12714.516 us; speedup 1.0000x reference)
//
#include <hip/hip_runtime.h>
#include <cmath>

// Problem constants
#define Bn 32
#define Tn 128
#define En 512
#define Hn 1024
// 4H = 4096

// ---------------- state init / finalize ----------------
__global__ __launch_bounds__(256) void init_state(const float* __restrict__ h0,
                                                  const float* __restrict__ c0,
                                                  float* __restrict__ hT,
                                                  float* __restrict__ cT) {
  int idx = blockIdx.x * 256 + threadIdx.x;  // 0..32767
  int u = idx >> 5, b = idx & 31;
  hT[idx] = h0[b * Hn + u];
  cT[idx] = c0[b * Hn + u];
}

__global__ __launch_bounds__(256) void finalize_state(const float* __restrict__ hT,
                                                      const float* __restrict__ cT,
                                                      float* __restrict__ out) {
  int idx = blockIdx.x * 256 + threadIdx.x;  // 0..32767
  int b = idx >> 10, u = idx & 1023;
  out[idx] = hT[u * 32 + b];
  out[32768 + idx] = cT[u * 32 + b];
}

// ---------------- U transpose: U (H,4H) -> Ut (4H,H) ----------------
__global__ __launch_bounds__(256) void transpose_U(const float* __restrict__ U,
                                                   float* __restrict__ Ut) {
  __shared__ float tile[32][33];
  int bx = blockIdx.x, by = blockIdx.y;  // bx: col tile (of 4096), by: row tile (of 1024)
  int x = threadIdx.x & 31, y = threadIdx.x >> 5;  // 32 x 8
#pragma unroll
  for (int i = 0; i < 4; ++i) {
    int r = by * 32 + y + i * 8;
    tile[y + i * 8][x] = U[(size_t)r * 4096 + bx * 32 + x];
  }
  __syncthreads();
#pragma unroll
  for (int i = 0; i < 4; ++i) {
    int c = bx * 32 + y + i * 8;
    Ut[(size_t)c * 1024 + by * 32 + x] = tile[x][y + i * 8];
  }
}

// ---------------- fp32 GEMM with bias (+optional relu) ----------------
// C[perm(r)][col] = sum_k A[r][k]*B[k][col] + bias[col]
// PERM 0: orow=r ; PERM 1: r=b*T+t -> orow=t*32+b ; PERM 2: r=t*32+b -> orow=b*T+t
template <int PERM>
__global__ __launch_bounds__(256) void gemm_bias(const float* __restrict__ A,
                                                 const float* __restrict__ B,
                                                 const float* __restrict__ bias,
                                                 float* __restrict__ C, int M, int N,
                                                 int K, int relu) {
  __shared__ float As[16][128];
  __shared__ float Bs[16][128];
  const int tid = threadIdx.x;
  const int bx = blockIdx.x, by = blockIdx.y;
  const int tx = tid & 15, ty = tid >> 4;
  const int ar = tid >> 2, af = tid & 3;     // A loads: rows ar, ar+64; k-quad af
  const int bkr = tid >> 4, bcf = tid & 15;  // B loads: k-row bkr; col-quads
  float acc[8][8];
#pragma unroll
  for (int i = 0; i < 8; ++i)
#pragma unroll
    for (int j = 0; j < 8; ++j) acc[i][j] = 0.f;

  const float* Ab = A + (size_t)(by * 128) * K;
  const float* Bb = B + bx * 128;

  for (int k0 = 0; k0 < K; k0 += 16) {
    float4 a0 = *(const float4*)(Ab + (size_t)ar * K + k0 + af * 4);
    float4 a1 = *(const float4*)(Ab + (size_t)(ar + 64) * K + k0 + af * 4);
    float4 b0 = *(const float4*)(Bb + (size_t)(k0 + bkr) * N + bcf * 4);
    float4 b1 = *(const float4*)(Bb + (size_t)(k0 + bkr) * N + 64 + bcf * 4);
    __syncthreads();
    As[af * 4 + 0][ar] = a0.x;
    As[af * 4 + 1][ar] = a0.y;
    As[af * 4 + 2][ar] = a0.z;
    As[af * 4 + 3][ar] = a0.w;
    As[af * 4 + 0][ar + 64] = a1.x;
    As[af * 4 + 1][ar + 64] = a1.y;
    As[af * 4 + 2][ar + 64] = a1.z;
    As[af * 4 + 3][ar + 64] = a1.w;
    *(float4*)&Bs[bkr][bcf * 4] = b0;
    *(float4*)&Bs[bkr][64 + bcf * 4] = b1;
    __syncthreads();
#pragma unroll
    for (int k = 0; k < 16; ++k) {
      float xr[8], yr[8];
      *(float4*)&xr[0] = *(const float4*)&As[k][ty * 8];
      *(float4*)&xr[4] = *(const float4*)&As[k][ty * 8 + 4];
      *(float4*)&yr[0] = *(const float4*)&Bs[k][tx * 4];
      *(float4*)&yr[4] = *(const float4*)&Bs[k][64 + tx * 4];
#pragma unroll
      for (int i = 0; i < 8; ++i)
#pragma unroll
        for (int j = 0; j < 8; ++j) acc[i][j] += xr[i] * yr[j];
    }
  }

  const int c0 = bx * 128 + tx * 4;
  const int c1 = bx * 128 + 64 + tx * 4;
  float4 bs0 = *(const float4*)(bias + c0);
  float4 bs1 = *(const float4*)(bias + c1);
#pragma unroll
  for (int i = 0; i < 8; ++i) {
    int r = by * 128 + ty * 8 + i;
    int orow;
    if constexpr (PERM == 0)
      orow = r;
    else if constexpr (PERM == 1)
      orow = (r & 127) * 32 + (r >> 7);
    else
      orow = (r & 31) * 128 + (r >> 5);
    float4 v0, v1;
    v0.x = acc[i][0] + bs0.x;
    v0.y = acc[i][1] + bs0.y;
    v0.z = acc[i][2] + bs0.z;
    v0.w = acc[i][3] + bs0.w;
    v1.x = acc[i][4] + bs1.x;
    v1.y = acc[i][5] + bs1.y;
    v1.z = acc[i][6] + bs1.z;
    v1.w = acc[i][7] + bs1.w;
    if (relu) {
      v0.x = fmaxf(v0.x, 0.f); v0.y = fmaxf(v0.y, 0.f);
      v0.z = fmaxf(v0.z, 0.f); v0.w = fmaxf(v0.w, 0.f);
      v1.x = fmaxf(v1.x, 0.f); v1.y = fmaxf(v1.y, 0.f);
      v1.z = fmaxf(v1.z, 0.f); v1.w = fmaxf(v1.w, 0.f);
    }
    *(float4*)(C + (size_t)orow * N + c0) = v0;
    *(float4*)(C + (size_t)orow * N + c1) = v1;
  }
}

// ---------------- recurrent step ----------------
// z[b][col] = xWt[t][b][col] + sum_k h[k][b] * Ut[col][k]
// Block: 4 hidden units (all 4 gates, all 32 batches). 256 threads:
//   slot s = tid&31 : uu = s&3 (unit), bg = s>>2 (batch group of 4)
//   kc = tid>>5 (k-split of 8, 128 k each, staged in 4 phases of 256 k)
__global__ __launch_bounds__(256) void lstm_step(const float* __restrict__ xWt,
                                                 const float* __restrict__ Ut,
                                                 const float* __restrict__ hin,
                                                 float* __restrict__ hout,
                                                 float* __restrict__ cT,
                                                 float* __restrict__ seq, int t) {
  __shared__ float hs[256 * 32];    // 32KB: h chunk [k][b]
  __shared__ float red[256 * 17];   // padded reduction buffer
  const int tid = threadIdx.x;
  const int s = tid & 31, kc = tid >> 5;
  const int uu = s & 3, bg = s >> 2;
  const int u = blockIdx.x * 4 + uu;
  const int b0 = bg * 4;

  float acc[4][4];
#pragma unroll
  for (int g = 0; g < 4; ++g)
#pragma unroll
    for (int j = 0; j < 4; ++j) acc[g][j] = 0.f;

  const int kbase = kc * 32;  // this thread's k-window within a 256-chunk

  for (int ph = 0; ph < 4; ++ph) {
    if (ph) __syncthreads();  // everyone done reading previous chunk
    {
      const float4* src = (const float4*)(hin + ph * 256 * 32);
      float4* dst = (float4*)hs;
#pragma unroll
      for (int i = 0; i < 8; ++i) dst[tid + 256 * i] = src[tid + 256 * i];
    }
    __syncthreads();
    const float* Ui = Ut + ((size_t)(0 * 1024 + u)) * 1024 + ph * 256 + kbase;
    const float* Uf = Ut + ((size_t)(1 * 1024 + u)) * 1024 + ph * 256 + kbase;
    const float* Ug = Ut + ((size_t)(2 * 1024 + u)) * 1024 + ph * 256 + kbase;
    const float* Uo = Ut + ((size_t)(3 * 1024 + u)) * 1024 + ph * 256 + kbase;
#pragma unroll
    for (int k4 = 0; k4 < 32; k4 += 4) {
      float wi[4], wf[4], wg[4], wo[4];
      *(float4*)wi = *(const float4*)(Ui + k4);
      *(float4*)wf = *(const float4*)(Uf + k4);
      *(float4*)wg = *(const float4*)(Ug + k4);
      *(float4*)wo = *(const float4*)(Uo + k4);
#pragma unroll
      for (int kk = 0; kk < 4; ++kk) {
        float4 h4 = *(const float4*)(hs + ((kbase + k4 + kk) << 5) + b0);
        acc[0][0] += wi[kk] * h4.x; acc[0][1] += wi[kk] * h4.y;
        acc[0][2] += wi[kk] * h4.z; acc[0][3] += wi[kk] * h4.w;
        acc[1][0] += wf[kk] * h4.x; acc[1][1] += wf[kk] * h4.y;
        acc[1][2] += wf[kk] * h4.z; acc[1][3] += wf[kk] * h4.w;
        acc[2][0] += wg[kk] * h4.x; acc[2][1] += wg[kk] * h4.y;
        acc[2][2] += wg[kk] * h4.z; acc[2][3] += wg[kk] * h4.w;
        acc[3][0] += wo[kk] * h4.x; acc[3][1] += wo[kk] * h4.y;
        acc[3][2] += wo[kk] * h4.z; acc[3][3] += wo[kk] * h4.w;
      }
    }
  }

  // tree reduce over kc (8 partials)
#pragma unroll
  for (int i = 0; i < 16; ++i) red[tid * 17 + i] = acc[i >> 2][i & 3];
  __syncthreads();
  for (int half = 4; half >= 1; half >>= 1) {
    if (kc < half) {
#pragma unroll
      for (int i = 0; i < 16; ++i)
        acc[i >> 2][i & 3] += red[(s + 32 * (kc + half)) * 17 + i];
      if (half > 1) {
#pragma unroll
        for (int i = 0; i < 16; ++i) red[tid * 17 + i] = acc[i >> 2][i & 3];
      }
    }
    __syncthreads();
  }

  if (kc == 0) {
    const float* xrow_base = xWt + (size_t)t * 32 * 4096;
#pragma unroll
    for (int jj = 0; jj < 4; ++jj) {
      int b = b0 + jj;
      const float* xrow = xrow_base + (size_t)b * 4096;
      float zi = acc[0][jj] + xrow[u];
      float zf = acc[1][jj] + xrow[1024 + u];
      float zg = acc[2][jj] + xrow[2048 + u];
      float zo = acc[3][jj] + xrow[3072 + u];
      float gi = 1.f / (1.f + expf(-zi));
      float gf = 1.f / (1.f + expf(-zf));
      float gg = fmaxf(zg, 0.f);
      float go = 1.f / (1.f + expf(-zo));
      int idx = u * 32 + b;
      float cn = gf * cT[idx] + gi * gg;
      cT[idx] = cn;
      float hn = go * fmaxf(cn, 0.f);
      hout[idx] = hn;
      seq[((size_t)t * 32 + b) * 1024 + u] = hn;
    }
  }
}

// ---------------- launch ----------------
extern "C" void kernel_launch(void* const* d_in, const int* in_sizes, int n_in,
                              void* d_out, int out_size, void* d_ws, size_t ws_size,
                              hipStream_t stream) {
  const float* x = (const float*)d_in[0];
  const float* h0 = (const float*)d_in[1];
  const float* c0 = (const float*)d_in[2];
  const float* W[4] = {(const float*)d_in[3], (const float*)d_in[6],
                       (const float*)d_in[9], (const float*)d_in[12]};
  const float* U[4] = {(const float*)d_in[4], (const float*)d_in[7],
                       (const float*)d_in[10], (const float*)d_in[13]};
  const float* bv[4] = {(const float*)d_in[5], (const float*)d_in[8],
                        (const float*)d_in[11], (const float*)d_in[14]};
  const float* Wd1 = (const float*)d_in[15];
  const float* bd1 = (const float*)d_in[16];
  const float* Wd2 = (const float*)d_in[17];
  const float* bd2 = (const float*)d_in[18];
  float* out = (float*)d_out;

  float* ws = (float*)d_ws;
  float* xWt = ws;                      // (T,B,4H) 16,777,216
  float* seqA = xWt + 16777216;         // (T,B,H)   4,194,304
  float* seqB = seqA + 4194304;         //           4,194,304
  float* Ut = seqB + 4194304;           // (4H,H)    4,194,304
  float* hA = Ut + 4194304;             // (H,B)     32,768
  float* hB = hA + 32768;               //           32,768
  float* cT = hB + 32768;               //           32,768

  init_state<<<128, 256, 0, stream>>>(h0, c0, hA, cT);

  float* bufs[2] = {seqA, seqB};
  const float* seqPrev = nullptr;
  for (int l = 0; l < 4; ++l) {
    transpose_U<<<dim3(128, 32), 256, 0, stream>>>(U[l], Ut);
    if (l == 0) {
      gemm_bias<1><<<dim3(32, 32), 256, 0, stream>>>(x, W[0], bv[0], xWt, 4096,
                                                     4096, 512, 0);
    } else {
      gemm_bias<0><<<dim3(32, 32), 256, 0, stream>>>(seqPrev, W[l], bv[l], xWt,
                                                     4096, 4096, 1024, 0);
    }
    float* seqOut = bufs[l & 1];
    for (int t = 0; t < 128; ++t) {
      const float* hi = (t & 1) ? hB : hA;
      float* ho = (t & 1) ? hA : hB;
      lstm_step<<<256, 256, 0, stream>>>(xWt, Ut, hi, ho, cT, seqOut, t);
    }
    seqPrev = seqOut;
  }

  // dense head: seqB (T,B,H) -> relu(.@Wd1+bd1) -> seqA -> .@Wd2+bd2 -> d_out (B,T,E)
  gemm_bias<0><<<dim3(8, 32), 256, 0, stream>>>(seqB, Wd1, bd1, seqA, 4096, 1024,
                                                1024, 1);
  gemm_bias<2><<<dim3(4, 32), 256, 0, stream>>>(seqA, Wd2, bd2, out, 4096, 512,
                                                1024, 0);
  finalize_state<<<128, 256, 0, stream>>>(hA, cT, out + 2097152);
}

// Round 2
// 7183.036 us; speedup vs baseline: 1.7701x; 1.7701x over previous
//
#include <hip/hip_runtime.h>
#include <cmath>

// B=32, T=128, E=512, H=1024, 4H=4096
typedef __attribute__((ext_vector_type(8))) short short8;
typedef __attribute__((ext_vector_type(4))) float f32x4;

__device__ inline short bf16r(float x) {
  union { float f; unsigned u; } v; v.f = x;
  unsigned r = (v.u + 0x7fff + ((v.u >> 16) & 1)) >> 16;
  return (short)r;
}
__device__ inline float bf2f(short s) {
  union { unsigned u; float f; } v; v.u = ((unsigned)(unsigned short)s) << 16;
  return v.f;
}

// ---------- small prep kernels ----------
__global__ __launch_bounds__(256) void init2(const float* __restrict__ h0,
                                             const float* __restrict__ c0,
                                             short* __restrict__ h,
                                             float* __restrict__ c) {
  int idx = blockIdx.x * 256 + threadIdx.x;  // 0..32767, (b,u) row-major
  h[idx] = bf16r(h0[idx]);
  c[idx] = c0[idx];
}

__global__ __launch_bounds__(256) void finalize2(const short* __restrict__ h,
                                                 const float* __restrict__ c,
                                                 float* __restrict__ out) {
  int idx = blockIdx.x * 256 + threadIdx.x;  // 0..32767
  out[idx] = bf2f(h[idx]);
  out[32768 + idx] = c[idx];
}

// x (B,T,E) fp32 -> xb rows r=t*32+b, (4096,512) bf16
__global__ __launch_bounds__(256) void cast_x(const float* __restrict__ x,
                                              short* __restrict__ xb) {
  int idx = blockIdx.x * 256 + threadIdx.x;  // 0..2097151
  int e = idx & 511, t = (idx >> 9) & 127, b = idx >> 16;
  xb[(((t << 5) + b) << 9) + e] = bf16r(x[idx]);
}

// permuted biases for the 4 layers: bp[l][n'] = b_l[(n'&3)*1024 + (n'>>2)]
__global__ __launch_bounds__(256) void bias_perm(const float* __restrict__ b1,
                                                 const float* __restrict__ b2,
                                                 const float* __restrict__ b3,
                                                 const float* __restrict__ b4,
                                                 float* __restrict__ bp) {
  int idx = blockIdx.x * 256 + threadIdx.x;  // 0..16383
  int l = idx >> 12, c = idx & 4095;
  const float* s = (l == 0) ? b1 : (l == 1) ? b2 : (l == 2) ? b3 : b4;
  bp[idx] = s[((c & 3) << 10) | (c >> 2)];
}

// in fp32 (R,C) -> out bf16 (C,R); GPERM: out-row n' = (c&1023)*4 + (c>>10)
template <bool GPERM>
__global__ __launch_bounds__(256) void transpose_cast(const float* __restrict__ in,
                                                      short* __restrict__ out,
                                                      int R, int C) {
  __shared__ float tile[32][33];
  int c0 = blockIdx.x * 32, r0 = blockIdx.y * 32;
  int x = threadIdx.x & 31, y = threadIdx.x >> 5;  // 32 x 8
#pragma unroll
  for (int i = 0; i < 4; ++i)
    tile[y + i * 8][x] = in[(size_t)(r0 + y + i * 8) * C + c0 + x];
  __syncthreads();
#pragma unroll
  for (int i = 0; i < 4; ++i) {
    int c = c0 + y + i * 8;
    int n = GPERM ? (((c & 1023) << 2) | (c >> 10)) : c;
    out[(size_t)n * R + r0 + x] = bf16r(tile[x][y + i * 8]);
  }
}

// ---------- bf16 MFMA GEMM ----------
// A (M,K) bf16 row-major; Bt (N,K) bf16 row-major; C = A·Bt^T + bias
// MODE 1: fp32 out xWp[t][col][b], rows r = t*32+b  (float4 stores)
// MODE 2: bf16 out row-major (M,N), relu
// MODE 3: fp32 out, orow = (r&31)*128 + (r>>5)   (final (B,T,E))
template <int MODE>
__global__ __launch_bounds__(256) void gemm_bf16(const short* __restrict__ A,
                                                 const short* __restrict__ Bt,
                                                 const float* __restrict__ bias,
                                                 void* __restrict__ Cout,
                                                 int M, int N, int K) {
  __shared__ short As[128 * 40];
  __shared__ short Bs[128 * 40];
  const int tid = threadIdx.x;
  const int lane = tid & 63, wave = tid >> 6;
  const int lrow = lane & 15, lk = lane >> 4;
  const int m0 = (wave >> 1) * 64, n0 = (wave & 1) * 64;
  const int r = tid & 127, half = tid >> 7;
  const int mbase = blockIdx.y * 128, nbase = blockIdx.x * 128;

  f32x4 acc[4][4] = {};

  const short* Ab = A + (size_t)(mbase + r) * K + half * 16;
  const short* Bb = Bt + (size_t)(nbase + r) * K + half * 16;
  short* AsW = As + r * 40 + half * 16;
  short* BsW = Bs + r * 40 + half * 16;

  for (int k0 = 0; k0 < K; k0 += 32) {
    short8 av0 = *(const short8*)(Ab + k0);
    short8 av1 = *(const short8*)(Ab + k0 + 8);
    short8 bv0 = *(const short8*)(Bb + k0);
    short8 bv1 = *(const short8*)(Bb + k0 + 8);
    __syncthreads();
    *(short8*)(AsW) = av0;
    *(short8*)(AsW + 8) = av1;
    *(short8*)(BsW) = bv0;
    *(short8*)(BsW + 8) = bv1;
    __syncthreads();
    short8 af[4], bfr[4];
#pragma unroll
    for (int i = 0; i < 4; ++i)
      af[i] = *(const short8*)(As + (m0 + i * 16 + lrow) * 40 + lk * 8);
#pragma unroll
    for (int i = 0; i < 4; ++i)
      bfr[i] = *(const short8*)(Bs + (n0 + i * 16 + lrow) * 40 + lk * 8);
#pragma unroll
    for (int i = 0; i < 4; ++i)
#pragma unroll
      for (int j = 0; j < 4; ++j)
        acc[i][j] = __builtin_amdgcn_mfma_f32_16x16x32_bf16(af[i], bfr[j],
                                                            acc[i][j], 0, 0, 0);
  }

#pragma unroll
  for (int i = 0; i < 4; ++i) {
    const int grow0 = mbase + m0 + i * 16 + lk * 4;
#pragma unroll
    for (int j = 0; j < 4; ++j) {
      const int gcol = nbase + n0 + j * 16 + lrow;
      const float bv = bias[gcol];
      f32x4 v = acc[i][j];
      if constexpr (MODE == 1) {
        int t = grow0 >> 5, b = grow0 & 31;
        f32x4 o;
        o[0] = v[0] + bv; o[1] = v[1] + bv; o[2] = v[2] + bv; o[3] = v[3] + bv;
        *(f32x4*)((float*)Cout + ((size_t)t * 4096 + gcol) * 32 + b) = o;
      } else if constexpr (MODE == 2) {
        short* o = (short*)Cout;
#pragma unroll
        for (int jj = 0; jj < 4; ++jj)
          o[(size_t)(grow0 + jj) * N + gcol] = bf16r(fmaxf(v[jj] + bv, 0.f));
      } else {
        float* o = (float*)Cout;
#pragma unroll
        for (int jj = 0; jj < 4; ++jj) {
          int rr = grow0 + jj;
          int orow = ((rr & 31) << 7) | (rr >> 5);
          o[(size_t)orow * N + gcol] = v[jj] + bv;
        }
      }
    }
  }
}

// ---------- MFMA recurrent step ----------
// xWp (T,4096,32) fp32 in C-fragment layout; Utp (4096,1024) bf16 gate-interleaved;
// h (32,1024) bf16; c (32,1024) fp32; seq (T,32,1024) bf16.
// 128 blocks x 128 threads; wave covers 16 cols (4 units x 4 gates).
__global__ __launch_bounds__(128) void lstm_step_mfma(
    const float* __restrict__ xWp, const short* __restrict__ Utp,
    const short* __restrict__ hin, short* __restrict__ hout,
    float* __restrict__ cst, short* __restrict__ seq, int t) {
  const int lane = threadIdx.x & 63, wave = threadIdx.x >> 6;
  const int lrow = lane & 15, lk = lane >> 4;
  const int col = blockIdx.x * 32 + wave * 16 + lrow;

  const float* xb = xWp + ((size_t)t * 4096 + col) * 32;
  f32x4 acc0 = *(const f32x4*)(xb + lk * 4);
  f32x4 acc1 = *(const f32x4*)(xb + 16 + lk * 4);

  const short* Ub = Utp + (size_t)col * 1024 + lk * 8;
  const short* ha = hin + lrow * 1024 + lk * 8;
  const short* hb = hin + (16 + lrow) * 1024 + lk * 8;
#pragma unroll 4
  for (int k0 = 0; k0 < 1024; k0 += 32) {
    short8 bfr = *(const short8*)(Ub + k0);
    short8 a0 = *(const short8*)(ha + k0);
    short8 a1 = *(const short8*)(hb + k0);
    acc0 = __builtin_amdgcn_mfma_f32_16x16x32_bf16(a0, bfr, acc0, 0, 0, 0);
    acc1 = __builtin_amdgcn_mfma_f32_16x16x32_bf16(a1, bfr, acc1, 0, 0, 0);
  }

  const int g = col & 3, u = col >> 2;
#pragma unroll
  for (int h = 0; h < 2; ++h) {
#pragma unroll
    for (int jj = 0; jj < 4; ++jj) {
      float v = h ? acc1[jj] : acc0[jj];
      float zi = __shfl(v, (lane & ~3) | 0, 64);
      float zf = __shfl(v, (lane & ~3) | 1, 64);
      float zg = __shfl(v, (lane & ~3) | 2, 64);
      float zo = __shfl(v, (lane & ~3) | 3, 64);
      if (g == 0) {
        int b = h * 16 + lk * 4 + jj;
        float gi = 1.f / (1.f + expf(-zi));
        float gf = 1.f / (1.f + expf(-zf));
        float gg = fmaxf(zg, 0.f);
        float go = 1.f / (1.f + expf(-zo));
        int idx = b * 1024 + u;
        float cn = gf * cst[idx] + gi * gg;
        cst[idx] = cn;
        short hb16 = bf16r(go * fmaxf(cn, 0.f));
        hout[idx] = hb16;
        seq[(((size_t)t << 5) + b) * 1024 + u] = hb16;
      }
    }
  }
}

// ---------- launch ----------
extern "C" void kernel_launch(void* const* d_in, const int* in_sizes, int n_in,
                              void* d_out, int out_size, void* d_ws, size_t ws_size,
                              hipStream_t stream) {
  const float* x = (const float*)d_in[0];
  const float* h0 = (const float*)d_in[1];
  const float* c0 = (const float*)d_in[2];
  const float* W[4] = {(const float*)d_in[3], (const float*)d_in[6],
                       (const float*)d_in[9], (const float*)d_in[12]};
  const float* U[4] = {(const float*)d_in[4], (const float*)d_in[7],
                       (const float*)d_in[10], (const float*)d_in[13]};
  const float* bv[4] = {(const float*)d_in[5], (const float*)d_in[8],
                        (const float*)d_in[11], (const float*)d_in[14]};
  const float* Wd1 = (const float*)d_in[15];
  const float* bd1 = (const float*)d_in[16];
  const float* Wd2 = (const float*)d_in[17];
  const float* bd2 = (const float*)d_in[18];
  float* out = (float*)d_out;

  float* ws = (float*)d_ws;
  float* xWp = ws;                             // 16,777,216 f
  short* seq = (short*)(ws + 16777216);        // 4,194,304 bf16
  short* D1 = (short*)(ws + 18874368);         // 4,194,304 bf16
  short* Utp = (short*)(ws + 20971520);        // 4,194,304 bf16
  short* Wtp = (short*)(ws + 23068672);        // 4,194,304 bf16
  short* xb = (short*)(ws + 25165824);         // 2,097,152 bf16
  short* hA = (short*)(ws + 26214400);         // 32,768 bf16
  short* hB = (short*)(ws + 26230784);         // 32,768 bf16
  float* cst = ws + 26247168;                  // 32,768 f
  float* bp = ws + 26279936;                   // 16,384 f

  init2<<<128, 256, 0, stream>>>(h0, c0, hA, cst);
  cast_x<<<8192, 256, 0, stream>>>(x, xb);
  bias_perm<<<64, 256, 0, stream>>>(bv[0], bv[1], bv[2], bv[3], bp);

  for (int l = 0; l < 4; ++l) {
    const int K = (l == 0) ? 512 : 1024;
    transpose_cast<true><<<dim3(128, 32), 256, 0, stream>>>(U[l], Utp, 1024, 4096);
    transpose_cast<true><<<dim3(128, K / 32), 256, 0, stream>>>(W[l], Wtp, K, 4096);
    const short* A = (l == 0) ? xb : seq;
    gemm_bf16<1><<<dim3(32, 32), 256, 0, stream>>>(A, Wtp, bp + l * 4096, xWp,
                                                   4096, 4096, K);
    for (int t = 0; t < 128; ++t) {
      const short* hi = (t & 1) ? hB : hA;
      short* ho = (t & 1) ? hA : hB;
      lstm_step_mfma<<<128, 128, 0, stream>>>(xWp, Utp, hi, ho, cst, seq, t);
    }
  }

  // dense head
  transpose_cast<false><<<dim3(32, 32), 256, 0, stream>>>(Wd1, Wtp, 1024, 1024);
  gemm_bf16<2><<<dim3(8, 32), 256, 0, stream>>>(seq, Wtp, bd1, D1, 4096, 1024, 1024);
  transpose_cast<false><<<dim3(16, 32), 256, 0, stream>>>(Wd2, Wtp, 1024, 512);
  gemm_bf16<3><<<dim3(4, 32), 256, 0, stream>>>(D1, Wtp, bd2, out, 4096, 512, 1024);

  finalize2<<<128, 256, 0, stream>>>(hA, cst, out + 2097152);
}